// Round 6
// baseline (172.309 us; speedup 1.0000x reference)
//
#include <hip/hip_runtime.h>

#define B_   8
#define C_   256
#define W_   8192
#define F_   256
#define KK   3
#define KC   768            // KK * C_
#define WP   (W_ + 2)       // padded rows in featT (zero row at w=-1 and w=W)
#define COEF 0.03608439182435161f   // 1/sqrt(3*256)

// conv_mod geometry: BM=256 (all of F), BN=128 (w), BK=64, 8 waves (4M x 2N),
// wave-tile 64x64. A: double-buffer (2 x 32 KiB), B: ring-3 (3 x 16 KiB).
#define BN_    128
#define BKc    64
#define NT     12           // 768 / 64 K-tiles
#define ASLOTU 16384        // ushorts per A slot (256 rows x 64)
#define BBASEU 32768        // ushort offset of B region (after 2 A slots)
#define BSLOTU 8192         // ushorts per B slot (128 rows x 64)

using f32x16 = __attribute__((ext_vector_type(16))) float;
using bf16x8 = __attribute__((ext_vector_type(8))) __bf16;

#define AS1(p) ((const __attribute__((address_space(1))) void*)(p))
#define AS3(p) ((__attribute__((address_space(3))) void*)(p))

__device__ __forceinline__ unsigned short f2bf(float x) {
    union { float f; unsigned int u; } v; v.f = x;
    unsigned int u = v.u;
    u += 0x7FFFu + ((u >> 16) & 1u);   // RNE
    return (unsigned short)(u >> 16);
}

// Merged prep: blocks 0..7 compute denom (long pole, dispatched first);
// blocks 8..775 transpose kernel -> kT and zero featT's pad rows.
__global__ __launch_bounds__(256) void prep_w(const float* __restrict__ kern,
                                              const float* __restrict__ style,
                                              unsigned short* __restrict__ kT,
                                              float* __restrict__ denom,
                                              unsigned short* __restrict__ featT) {
    __shared__ float sst[C_];
    if (blockIdx.x < B_) {
        const int b = blockIdx.x, f = threadIdx.x;
        sst[f] = (style[b * C_ + f] + 1.0f) * COEF;
        __syncthreads();
        float sum = 0.f;
#pragma unroll 16
        for (int kc = 0; kc < KC; ++kc) {
            float w = kern[(size_t)kc * F_ + f] * sst[kc & 255];
            sum += w * w;
        }
        denom[b * F_ + f] = rsqrtf(sum);
    } else {
        const int idx = (blockIdx.x - B_) * 256 + threadIdx.x;   // ((k*256)+c)*256 + f
        const int f = idx & 255, kc = idx >> 8;
        kT[(size_t)f * KC + kc] = f2bf(kern[idx] * COEF);
        if (idx < 4096) {       // 8 b * 2 pad rows * 256 c
            const int b = idx >> 9, r = (idx >> 8) & 1, c = idx & 255;
            const size_t row = r ? (size_t)(WP - 1) : 0;
            featT[((size_t)b * WP + row) * C_ + c] = 0;
        }
    }
}

// featT[b][w+1][c] = bf16( feat[b][c][w] * (style[b][c]+1) )
__global__ __launch_bounds__(256) void prep_featT(const float* __restrict__ feat,
                                                  const float* __restrict__ style,
                                                  unsigned short* __restrict__ featT) {
    __shared__ float tile[64][65];   // [w][c], 65 pad -> conflict-free both phases
    const int tid = threadIdx.x;
    const int b = blockIdx.z, c0 = blockIdx.y * 64, w0 = blockIdx.x * 64;

    const int x4 = tid & 15, cl4 = tid >> 4;
#pragma unroll
    for (int p = 0; p < 4; ++p) {
        const int cl = cl4 + p * 16;
        const float s = style[b * C_ + c0 + cl] + 1.0f;
        float4 v = *(const float4*)(feat + ((size_t)b * C_ + c0 + cl) * W_ + w0 + x4 * 4);
        tile[x4 * 4 + 0][cl] = v.x * s;
        tile[x4 * 4 + 1][cl] = v.y * s;
        tile[x4 * 4 + 2][cl] = v.z * s;
        tile[x4 * 4 + 3][cl] = v.w * s;
    }
    __syncthreads();

    const int ch = tid & 7, wr = tid >> 3;   // ch: 8-c chunk, wr: 0..31
#pragma unroll
    for (int p = 0; p < 2; ++p) {
        const int w = wr + p * 32;
        unsigned int pk[4];
#pragma unroll
        for (int j = 0; j < 4; ++j) {
            float v0 = tile[w][ch * 8 + 2 * j];
            float v1 = tile[w][ch * 8 + 2 * j + 1];
            pk[j] = (unsigned int)f2bf(v0) | ((unsigned int)f2bf(v1) << 16);
        }
        uint4 u; u.x = pk[0]; u.y = pk[1]; u.z = pk[2]; u.w = pk[3];
        *(uint4*)(featT + ((size_t)b * WP + (w0 + w + 1)) * C_ + c0 + ch * 8) = u;
    }
}

// Main GEMM-conv, dual-barrier fine-interleave (8-phase-family, T3+T4+T5):
// 256(f) x 128(w) block tile, 512 threads = 8 waves (4M x 2N), wave-tile 64x64
// via 2(mi) x 2(ni) of 32x32x16 MFMA. BK=64 (128-B rows).
// LDS 112 KiB: A (kT) dbuf 2 x 32 KiB staged 1 tile ahead (L2-hot, short
// latency); B (featT) ring-3 3 x 16 KiB staged 2 tiles ahead (HBM latency).
// Per K-tile, 2 phases (kh-halves). Phase body:
//   {glds stage} {8 ds_read_b128} {sched_barrier; s_barrier} {setprio(1)
//    8 MFMA setprio(0)} {[boundary only: vmcnt(2)]} {sched_barrier; s_barrier}
// The first barrier lets the ds_read latency span the barrier-sync and gives
// the CU a reads-vs-MFMA wave role-split (m196/m248: this fine interleave is
// the 8-phase lever). Waits are always immediately pre-barrier (cross-wave
// visibility). In-order vmcnt trace at boundary of tile k:
//   outstanding = B(k+1):2 (issued k-1,p1) + A(k+1):4 (k,p0) + B(k+2):2 (k,p1)
//   vmcnt(2) retires exactly {B(k+1), A(k+1)} -- never drains to 0.
// Bank swizzle: phys 16-B chunk p at row r holds logical p ^ (r&7); applied on
// the global SOURCE for staging (LDS dest linear, rule #21) and on read-side
// chunk index (row&7 == la&7). XCD swizzle: 512 blocks, lin%8 -> XCD chunk;
// each XCD owns one batch b (its 4-MB featT slice fits the private L2).
__global__ __launch_bounds__(512, 2) void conv_mod(
        const unsigned short* __restrict__ featT,
        const unsigned short* __restrict__ kT,
        const float* __restrict__ denom,
        float* __restrict__ out) {
    __shared__ __align__(16) unsigned short ring[BBASEU + 3 * BSLOTU];   // 112 KiB

    const int tid  = threadIdx.x;
    // ---- bijective XCD swizzle: 512 blocks = 8 XCDs x 64; XCD j computes the
    //      64 w-tiles of batch j ----
    const int lin  = blockIdx.y * 64 + blockIdx.x;
    const int swz  = (lin & 7) * 64 + (lin >> 3);
    const int b    = swz >> 6;
    const int w0   = (swz & 63) * BN_;
    const int lane = tid & 63, wave = tid >> 6;
    const int wm   = (wave >> 1) * 64;    // wave f-offset (4 M-waves)
    const int wn   = (wave & 1) * 64;     // wave w-offset (2 N-waves)
    const int la   = lane & 31, kq = lane >> 5;

    // ---- staging: source call g covers rows g*64..g*64+63 (8 KiB, all 8
    //      waves). thread tid -> row g*64+(tid>>3); source supplies logical
    //      chunk (tid&7)^(row&7). LDS dest wave-uniform; HW adds lane*16. ----
    const int srow = tid >> 3;
    const int sswz = ((tid & 7) ^ (srow & 7)) * 8;
    const unsigned short* aS0 = kT + (size_t)srow * KC + sswz;
    const unsigned short* bS0 = featT + ((size_t)b * WP + w0 + srow) * C_ + sswz;
    const int wdst = wave << 9;          // wave-uniform ushort offset: wave*512

    // ---- frag read offsets: row*64 + chunk*8, chunk = (kh*2+kq)^(la&7) ----
    int ck[4];
#pragma unroll
    for (int kh = 0; kh < 4; ++kh) ck[kh] = ((kh * 2 + kq) ^ (la & 7)) * 8;
    const int ra0 = (wm + la) * BKc;     // + mi*2048 + ck[kh], within A slot
    const int rb0 = (wn + la) * BKc;     // + ni*2048 + ck[kh], within B slot

    f32x16 acc[2][2] = {};

#define GLDS_A(g, kc, sb) __builtin_amdgcn_global_load_lds( \
        AS1(aS0 + (size_t)(g) * 64 * KC + (kc)), \
        AS3(ring + (sb) + (g) * 4096 + wdst), 16, 0, 0)
#define GLDS_B(g, kc, sb) __builtin_amdgcn_global_load_lds( \
        AS1(bS0 + (size_t)(g) * 64 * C_ + (kc)), \
        AS3(ring + BBASEU + (sb) + (g) * 4096 + wdst), 16, 0, 0)
#define SBAR() do { __builtin_amdgcn_sched_barrier(0); \
                    __builtin_amdgcn_s_barrier(); \
                    asm volatile("" ::: "memory"); } while (0)
#define VMW(n) do { __builtin_amdgcn_sched_barrier(0); \
                    asm volatile("s_waitcnt vmcnt(" #n ")" ::: "memory"); } while (0)

    // PHASE(Q): kh in {Q*2, Q*2+1}; reads 4 A-frags + 4 B-frags, 8 MFMA.
#define PHASE(Q) do { \
        bf16x8 av[2][2], bv[2][2]; \
        _Pragma("unroll") \
        for (int i = 0; i < 2; ++i) { \
            _Pragma("unroll") \
            for (int j = 0; j < 2; ++j) { \
                av[i][j] = *(const bf16x8*)&ab[ra0 + i * 2048 + ck[(Q) * 2 + j]]; \
                bv[i][j] = *(const bf16x8*)&bb[rb0 + i * 2048 + ck[(Q) * 2 + j]]; \
            } \
        } \
        SBAR(); \
        __builtin_amdgcn_s_setprio(1); \
        _Pragma("unroll") \
        for (int j = 0; j < 2; ++j) { \
            _Pragma("unroll") \
            for (int i = 0; i < 2; ++i) { \
                acc[i][0] = __builtin_amdgcn_mfma_f32_32x32x16_bf16(av[i][j], bv[0][j], acc[i][0], 0, 0, 0); \
                acc[i][1] = __builtin_amdgcn_mfma_f32_32x32x16_bf16(av[i][j], bv[1][j], acc[i][1], 0, 0, 0); \
            } \
        } \
        __builtin_amdgcn_s_setprio(0); \
    } while (0)

    // ---- prologue: A(0) -> slot0 (4), B(0) -> bslot0 (2), B(1) -> bslot1 (2);
    //      vmcnt(2) retires {A(0), B(0)} (oldest 6); B(1) stays in flight ----
    GLDS_A(0, 0, 0); GLDS_A(1, 0, 0); GLDS_A(2, 0, 0); GLDS_A(3, 0, 0);
    GLDS_B(0, 0, 0); GLDS_B(1, 0, 0);
    GLDS_B(0, BKc, BSLOTU); GLDS_B(1, BKc, BSLOTU);
    VMW(2);
    __builtin_amdgcn_s_barrier();
    asm volatile("" ::: "memory");

#pragma unroll 1
    for (int t = 0; t < NT; ++t) {
        const unsigned short* ab = ring + (t & 1) * ASLOTU;
        const unsigned short* bb = ring + BBASEU + (t % 3) * BSLOTU;
        const int an = (t + 1 < NT ? t + 1 : NT - 1) * BKc;   // tail: dummy
        const int bn = (t + 2 < NT ? t + 2 : NT - 1) * BKc;   // re-stages
        const int as = ((t + 1) & 1) * ASLOTU;
        const int bs = ((t + 2) % 3) * BSLOTU;

        // ---- p0 (kh 0,1): stage A(t+1), 4 loads ----
        GLDS_A(0, an, as); GLDS_A(1, an, as);
        GLDS_A(2, an, as); GLDS_A(3, an, as);
        PHASE(0);
        SBAR();

        // ---- p1 (kh 2,3): stage B(t+2), 2 loads; boundary wait vmcnt(2)
        //      retires {B(t+1), A(t+1)}, keeps B(t+2) in flight ----
        GLDS_B(0, bn, bs); GLDS_B(1, bn, bs);
        PHASE(1);
        VMW(2);
        SBAR();
    }
    // drain the dummy re-stages before LDS is deallocated at wave end
    asm volatile("s_waitcnt vmcnt(0)" ::: "memory");

    // ---- epilogue: C/D layout for 32x32: col=lane&31,
    //      row=(reg&3)+8*(reg>>2)+4*(lane>>5) [measured m74/m101] ----
    const int bofs = b * F_;
    float* obase = out + (size_t)bofs * W_ + w0;
#pragma unroll
    for (int mi = 0; mi < 2; ++mi) {
#pragma unroll
        for (int r = 0; r < 16; ++r) {
            const int frow = (r & 3) + 8 * (r >> 2) + 4 * kq;
            const int f = wm + mi * 32 + frow;
            const float d = denom[bofs + f];
            float* orow = obase + (size_t)f * W_ + wn + la;
            orow[0]  = acc[mi][0][r] * d;
            orow[32] = acc[mi][1][r] * d;
        }
    }
#undef GLDS_A
#undef GLDS_B
#undef SBAR
#undef VMW
#undef PHASE
}

extern "C" void kernel_launch(void* const* d_in, const int* in_sizes, int n_in,
                              void* d_out, int out_size, void* d_ws, size_t ws_size,
                              hipStream_t stream) {
    const float* feature = (const float*)d_in[0];   // [8,256,8192]
    const float* style   = (const float*)d_in[1];   // [8,256]
    const float* kern    = (const float*)d_in[2];   // [3,256,256]
    float* out = (float*)d_out;                     // [8,256,8192]

    // ws layout: kT (384 KiB) | denom (8 KiB) | featT (8*8194*256 bf16 = 32.0 MiB)
    unsigned short* kT    = (unsigned short*)d_ws;
    float*          denom = (float*)((char*)d_ws + (size_t)F_ * KC * 2);
    unsigned short* featT = (unsigned short*)((char*)d_ws + (size_t)F_ * KC * 2 + 8192);

    hipLaunchKernelGGL(prep_w,     dim3(KC + B_), dim3(256), 0, stream,
                       kern, style, kT, denom, featT);
    hipLaunchKernelGGL(prep_featT, dim3(W_ / 64, C_ / 64, B_), dim3(256), 0, stream,
                       feature, style, featT);
    hipLaunchKernelGGL(conv_mod,   dim3(W_ / BN_, B_), dim3(512), 0, stream,
                       featT, kT, denom, out);
}